// Round 9
// baseline (152.020 us; speedup 1.0000x reference)
//
#include <hip/hip_runtime.h>
#include <stdint.h>
#include <math.h>

#define HID 64
#define PI_F 3.14159262235897933f

// ---------- fused prep: quaternion table + tail histogram ----------
__global__ void prep(const float* __restrict__ rel, float4* __restrict__ quat, int nrel,
                     const int* __restrict__ eidx, int E, int* __restrict__ hist,
                     int qblocks) {
    if ((int)blockIdx.x < qblocks) {
        int i = blockIdx.x * blockDim.x + threadIdx.x;
        if (i >= nrel * HID) return;
        int r = i >> 6, j = i & 63;
        const float* base = rel + (size_t)r * 4 * HID;
        float rx = base[j];
        float ry = base[HID + j];
        float rz = base[2 * HID + j];
        float th = base[3 * HID + j];
        float theta = th * PI_F;
        float sn = sinf(theta);
        float w  = cosf(theta);
        float tx = sn * rx, ty = sn * ry, tz = sn * rz;
        float norm = sqrtf(tx * tx + ty * ty + tz * tz);
        float inv = 1.0f / fmaxf(norm, 1e-12f);
        float s = sqrtf(fmaxf(1.0f - w * w, 0.0f));
        quat[i] = make_float4(w, s * tx * inv, s * ty * inv, s * tz * inv);
    } else {
        int e = (blockIdx.x - qblocks) * blockDim.x + threadIdx.x;
        if (e >= E) return;
        atomicAdd(hist + eidx[2 * E + e], 1);
    }
}

// ---------- parallel exclusive scan of hist -> base (2 dispatches) ----------
__global__ void scan1(const int* __restrict__ hist, int* __restrict__ base,
                      int* __restrict__ partial, int n) {
    __shared__ int buf[256];
    int tid = threadIdx.x;
    int gid = blockIdx.x * 256 + tid;
    int v = (gid < n) ? hist[gid] : 0;
    buf[tid] = v;
    __syncthreads();
    #pragma unroll
    for (int off = 1; off < 256; off <<= 1) {
        int x = (tid >= off) ? buf[tid - off] : 0;
        __syncthreads();
        buf[tid] += x;
        __syncthreads();
    }
    if (gid < n) base[gid] = buf[tid] - v;        // exclusive within block
    if (tid == 255) partial[blockIdx.x] = buf[255];
}

// Every block redundantly scans the <=256 partials in LDS, applies its offset.
__global__ void scan23(int* __restrict__ base, int* __restrict__ base2,
                       const int* __restrict__ partial,
                       int nb, int n, int E) {
    __shared__ int buf[256];
    int tid = threadIdx.x;
    int v = (tid < nb) ? partial[tid] : 0;
    buf[tid] = v;
    __syncthreads();
    #pragma unroll
    for (int off = 1; off < 256; off <<= 1) {
        int x = (tid >= off) ? buf[tid - off] : 0;
        __syncthreads();
        buf[tid] += x;
        __syncthreads();
    }
    int bsum = ((int)blockIdx.x < nb) ? partial[blockIdx.x] : 0;
    int boff = buf[blockIdx.x] - bsum;            // exclusive prefix of this block
    int gid = blockIdx.x * 256 + tid;
    if (gid < n) {
        int bv = base[gid] + boff;
        base[gid] = bv;
        base2[gid] = bv;
    } else if (gid == n) {
        base[n] = E;                              // sentinel
    }
}

// ---------- scatter packed (head, rel) into tail-sorted position ----------
__global__ void scatter_hr(const int* __restrict__ eidx, int E,
                           int* __restrict__ base2,
                           int2* __restrict__ hr) {
    int e = blockIdx.x * blockDim.x + threadIdx.x;
    if (e >= E) return;
    int t = eidx[2 * E + e];
    int pos = atomicAdd(base2 + t, 1);
    hr[pos] = make_int2(eidx[e], eidx[E + e]);
}

// ---------- per-tail pass: 2 WAVES per segment, 16 lanes/edge, 4 edges/wave ----------
// No max-tracking (alpha bounded, validated R7/R8). Wave q of a pair takes
// 4-edge groups start+4q, start+4q+8, ...; partials merged via LDS (plain sums).
__global__ void __launch_bounds__(256)
seg_reduce(const float* __restrict__ ent,
           const float4* __restrict__ quat,
           const int2* __restrict__ hr,
           const int* __restrict__ base,
           int n_ent,
           float* __restrict__ out) {
    __shared__ float4 part[2][64];
    __shared__ float pdnm[2];
    const int lane = threadIdx.x & 63;
    const int wv   = threadIdx.x >> 6;    // 0..3
    const int pair = wv >> 1;             // segment slot within block
    const int q    = wv & 1;              // half within pair
    const int sub  = lane >> 4;           // edge slot 0..3
    const int j    = lane & 15;           // dim group: dims 4j..4j+3
    const int t    = blockIdx.x * 2 + pair;

    float dnm = 0.0f;
    float4 ax = make_float4(0.f, 0.f, 0.f, 0.f);
    float4 ay = ax, az = ax, aw = ax;

    int start = 0, end = 0;
    if (t < n_ent) { start = base[t]; end = base[t + 1]; }

    if (start < end) {
        int last = end - 1;
        const float4* krow = (const float4*)(ent + (size_t)t * (3 * HID));
        float4 kx = krow[j], ky = krow[16 + j], kz = krow[32 + j];

        for (int k0 = start + 4 * q; k0 < end; k0 += 8) {
            int e = k0 + sub;
            bool valid = (e < end);
            int2 her = hr[min(e, last)];
            const float4* h = (const float4*)(ent + (size_t)her.x * (3 * HID));
            float4 hx = h[j], hy = h[16 + j], hz = h[32 + j];
            const float4* qr = quat + (size_t)her.y * HID + 4 * j;
            float4 q0 = qr[0], q1 = qr[1], q2 = qr[2], q3 = qr[3];

            float4 qx, qy, qz, qw;
            float p = 0.0f;
            #define DO_DIM(F, Q) { \
                float ex = hx.F, ey = hy.F, ez = hz.F; \
                float w = Q.x, ux = Q.y, uy = Q.z, uz = Q.w; \
                float rqx = w * ex + uy * ez - uz * ey; \
                float rqy = w * ey + uz * ex - ux * ez; \
                float rqz = w * ez + ux * ey - uy * ex; \
                float rqw = -(ux * ex + uy * ey + uz * ez); \
                p += kx.F * rqx + ky.F * rqy + kz.F * rqz; \
                qx.F = rqx; qy.F = rqy; qz.F = rqz; qw.F = rqw; }
            DO_DIM(x, q0)
            DO_DIM(y, q1)
            DO_DIM(z, q2)
            DO_DIM(w, q3)
            #undef DO_DIM

            p += __shfl_xor(p, 1, 64);
            p += __shfl_xor(p, 2, 64);
            p += __shfl_xor(p, 4, 64);
            p += __shfl_xor(p, 8, 64);

            float pe = valid ? __expf(p * 0.0625f) : 0.0f;
            dnm += pe;
            ax.x += pe * qx.x; ax.y += pe * qx.y; ax.z += pe * qx.z; ax.w += pe * qx.w;
            ay.x += pe * qy.x; ay.y += pe * qy.y; ay.z += pe * qy.z; ay.w += pe * qy.w;
            az.x += pe * qz.x; az.y += pe * qz.y; az.z += pe * qz.z; az.w += pe * qz.w;
            aw.x += pe * qw.x; aw.y += pe * qw.y; aw.z += pe * qw.z; aw.w += pe * qw.w;
        }

        // cross-subwarp merge within the wave: plain sums
        #pragma unroll
        for (int mask = 16; mask <= 32; mask <<= 1) {
            dnm += __shfl_xor(dnm, mask, 64);
            ax.x += __shfl_xor(ax.x, mask, 64); ax.y += __shfl_xor(ax.y, mask, 64);
            ax.z += __shfl_xor(ax.z, mask, 64); ax.w += __shfl_xor(ax.w, mask, 64);
            ay.x += __shfl_xor(ay.x, mask, 64); ay.y += __shfl_xor(ay.y, mask, 64);
            ay.z += __shfl_xor(ay.z, mask, 64); ay.w += __shfl_xor(ay.w, mask, 64);
            az.x += __shfl_xor(az.x, mask, 64); az.y += __shfl_xor(az.y, mask, 64);
            az.z += __shfl_xor(az.z, mask, 64); az.w += __shfl_xor(az.w, mask, 64);
            aw.x += __shfl_xor(aw.x, mask, 64); aw.y += __shfl_xor(aw.y, mask, 64);
            aw.z += __shfl_xor(aw.z, mask, 64); aw.w += __shfl_xor(aw.w, mask, 64);
        }
    }

    // per-lane component selection (unnormalized partial)
    float4 lo = (sub & 1) ? ay : ax;
    float4 hi = (sub & 1) ? aw : az;
    float4 val = (sub & 2) ? hi : lo;

    // wave q==1 deposits its partial; wave q==0 merges + stores
    if (q == 1) {
        part[pair][lane] = val;
        if (lane == 0) pdnm[pair] = dnm;
    }
    __syncthreads();
    if (q == 0 && t < n_ent) {
        float4 v1 = part[pair][lane];
        float dtot = dnm + pdnm[pair];
        val.x += v1.x; val.y += v1.y; val.z += v1.z; val.w += v1.w;
        float inv = (dtot > 0.0f) ? 1.0f / dtot : 0.0f;
        val.x *= inv; val.y *= inv; val.z *= inv; val.w *= inv;
        float4* o4 = (float4*)(out + (size_t)t * (4 * HID));
        o4[lane] = val;
    }
}

extern "C" void kernel_launch(void* const* d_in, const int* in_sizes, int n_in,
                              void* d_out, int out_size, void* d_ws, size_t ws_size,
                              hipStream_t stream) {
    const float* ent  = (const float*)d_in[0];
    const float* rel  = (const float*)d_in[1];
    const int*   eidx = (const int*)d_in[2];
    float* out = (float*)d_out;

    const int n_ent = in_sizes[0] / (3 * HID);
    const int n_rel = in_sizes[1] / (4 * HID);
    const int E     = in_sizes[2] / 3;

    // Workspace layout
    int2* hr     = (int2*)d_ws;                     // E int2
    int*  hist   = (int*)(hr + E);                  // n_ent
    int*  base   = hist + n_ent;                    // n_ent + 1
    int*  base2  = base + n_ent + 1;                // n_ent
    int*  partial= base2 + n_ent;                   // <=256
    uintptr_t p = (uintptr_t)(partial + 256);
    p = (p + 15) & ~(uintptr_t)15;
    float4* quat = (float4*)p;                      // n_rel * HID

    hipMemsetAsync(hist, 0, (size_t)n_ent * sizeof(int), stream);

    const int qblocks  = (n_rel * HID + 255) / 256;
    const int eblocks1 = (E + 255) / 256;
    prep<<<qblocks + eblocks1, 256, 0, stream>>>(rel, quat, n_rel, eidx, E, hist, qblocks);

    const int nb = (n_ent + 255) / 256;             // 196 for n_ent=50000 (<=256)
    scan1<<<nb, 256, 0, stream>>>(hist, base, partial, n_ent);
    scan23<<<(n_ent + 1 + 255) / 256, 256, 0, stream>>>(base, base2, partial, nb, n_ent, E);

    scatter_hr<<<eblocks1, 256, 0, stream>>>(eidx, E, base2, hr);

    const int sblocks = (n_ent + 1) / 2;            // 2 segments per block
    seg_reduce<<<sblocks, 256, 0, stream>>>(ent, quat, hr, base, n_ent, out);
}

// Round 10
// 137.164 us; speedup vs baseline: 1.1083x; 1.1083x over previous
//
#include <hip/hip_runtime.h>
#include <stdint.h>
#include <math.h>

#define HID 64
#define PI_F 3.14159262235897933f

__device__ __forceinline__ unsigned short f2bf(float f) {   // round-to-nearest-even
    unsigned u = __float_as_uint(f);
    return (unsigned short)((u + 0x7FFFu + ((u >> 16) & 1u)) >> 16);
}
__device__ __forceinline__ float bflo(unsigned v) { return __uint_as_float(v << 16); }
__device__ __forceinline__ float bfhi(unsigned v) { return __uint_as_float(v & 0xFFFF0000u); }

// ---------- fused prep: bf16 quat table + tail histogram + bf16 entity copy ----------
__global__ void prep(const float* __restrict__ rel, uint2* __restrict__ quat16, int nrel,
                     const int* __restrict__ eidx, int E, int* __restrict__ hist,
                     const float* __restrict__ ent, uint4* __restrict__ ent16, int nconv,
                     int qblocks, int eblocks) {
    const int b = blockIdx.x;
    if (b < qblocks) {
        int i = b * 256 + threadIdx.x;
        if (i >= nrel * HID) return;
        int r = i >> 6, j = i & 63;
        const float* base = rel + (size_t)r * 4 * HID;
        float rx = base[j];
        float ry = base[HID + j];
        float rz = base[2 * HID + j];
        float th = base[3 * HID + j];
        float theta = th * PI_F;
        float sn = sinf(theta);
        float w  = cosf(theta);
        float tx = sn * rx, ty = sn * ry, tz = sn * rz;
        float norm = sqrtf(tx * tx + ty * ty + tz * tz);
        float inv = 1.0f / fmaxf(norm, 1e-12f);
        float s = sqrtf(fmaxf(1.0f - w * w, 0.0f));
        float ux = s * tx * inv, uy = s * ty * inv, uz = s * tz * inv;
        quat16[i] = make_uint2(((unsigned)f2bf(ux) << 16) | f2bf(w),
                               ((unsigned)f2bf(uz) << 16) | f2bf(uy));
    } else if (b < qblocks + eblocks) {
        int e = (b - qblocks) * 256 + threadIdx.x;
        if (e >= E) return;
        atomicAdd(hist + eidx[2 * E + e], 1);
    } else {
        int u = (b - qblocks - eblocks) * 256 + threadIdx.x;
        if (u >= nconv) return;
        const float4* src = (const float4*)ent + 2 * (size_t)u;
        float4 a = src[0], c = src[1];
        ent16[u] = make_uint4(((unsigned)f2bf(a.y) << 16) | f2bf(a.x),
                              ((unsigned)f2bf(a.w) << 16) | f2bf(a.z),
                              ((unsigned)f2bf(c.y) << 16) | f2bf(c.x),
                              ((unsigned)f2bf(c.w) << 16) | f2bf(c.z));
    }
}

// ---------- parallel exclusive scan of hist -> base (2 dispatches) ----------
__global__ void scan1(const int* __restrict__ hist, int* __restrict__ base,
                      int* __restrict__ partial, int n) {
    __shared__ int buf[256];
    int tid = threadIdx.x;
    int gid = blockIdx.x * 256 + tid;
    int v = (gid < n) ? hist[gid] : 0;
    buf[tid] = v;
    __syncthreads();
    #pragma unroll
    for (int off = 1; off < 256; off <<= 1) {
        int x = (tid >= off) ? buf[tid - off] : 0;
        __syncthreads();
        buf[tid] += x;
        __syncthreads();
    }
    if (gid < n) base[gid] = buf[tid] - v;
    if (tid == 255) partial[blockIdx.x] = buf[255];
}

__global__ void scan23(int* __restrict__ base, int* __restrict__ base2,
                       const int* __restrict__ partial,
                       int nb, int n, int E) {
    __shared__ int buf[256];
    int tid = threadIdx.x;
    int v = (tid < nb) ? partial[tid] : 0;
    buf[tid] = v;
    __syncthreads();
    #pragma unroll
    for (int off = 1; off < 256; off <<= 1) {
        int x = (tid >= off) ? buf[tid - off] : 0;
        __syncthreads();
        buf[tid] += x;
        __syncthreads();
    }
    int bsum = ((int)blockIdx.x < nb) ? partial[blockIdx.x] : 0;
    int boff = buf[blockIdx.x] - bsum;
    int gid = blockIdx.x * 256 + tid;
    if (gid < n) {
        int bv = base[gid] + boff;
        base[gid] = bv;
        base2[gid] = bv;
    } else if (gid == n) {
        base[n] = E;
    }
}

// ---------- scatter packed (head, rel) into tail-sorted position ----------
__global__ void scatter_hr(const int* __restrict__ eidx, int E,
                           int* __restrict__ base2,
                           int2* __restrict__ hr) {
    int e = blockIdx.x * blockDim.x + threadIdx.x;
    if (e >= E) return;
    int t = eidx[2 * E + e];
    int pos = atomicAdd(base2 + t, 1);
    hr[pos] = make_int2(eidx[e], eidx[E + e]);
}

// ---------- persistent per-tail pass: 16 lanes/edge, 4 edges/wave, bf16 gathers ----------
// No max-tracking (alpha bounded; validated R7/R8). BF16: head rows + quat in bf16
// (halves cache-line traffic); k row and all accumulation stay f32.
template <bool BF16>
__global__ void __launch_bounds__(256)
seg_reduce(const float* __restrict__ ent,
           const uint2* __restrict__ ent16,   // [n_ent][48] uint2 (bf16 pairs)
           const uint2* __restrict__ quat16,  // [nrel*HID] uint2 {ux|w, uz|uy}
           const int2* __restrict__ hr,
           const int* __restrict__ base,
           int n_ent,
           float* __restrict__ out) {
    const int lane = threadIdx.x & 63;
    const int sub = lane >> 4;            // edge slot 0..3
    const int j   = lane & 15;            // dim group: dims 4j..4j+3
    const int wid = (blockIdx.x * blockDim.x + threadIdx.x) >> 6;
    const int nw  = (gridDim.x * blockDim.x) >> 6;

    for (int t = wid; t < n_ent; t += nw) {
        int start = base[t];
        int end   = base[t + 1];
        float4* o4 = (float4*)(out + (size_t)t * (4 * HID));
        if (start == end) {
            o4[lane] = make_float4(0.f, 0.f, 0.f, 0.f);
            continue;
        }
        int last = end - 1;

        const float4* krow = (const float4*)(ent + (size_t)t * (3 * HID));
        float4 kx = krow[j], ky = krow[16 + j], kz = krow[32 + j];

        float dnm = 0.0f;
        float4 ax = make_float4(0.f, 0.f, 0.f, 0.f);
        float4 ay = ax, az = ax, aw = ax;

        for (int k0 = start; k0 < end; k0 += 4) {
            int e = k0 + sub;
            bool valid = (e < end);
            int2 her = hr[min(e, last)];

            float4 hx, hy, hz;
            if constexpr (BF16) {
                const uint2* h = ent16 + (size_t)her.x * 48;
                uint2 u0 = h[j], u1 = h[16 + j], u2 = h[32 + j];
                hx = make_float4(bflo(u0.x), bfhi(u0.x), bflo(u0.y), bfhi(u0.y));
                hy = make_float4(bflo(u1.x), bfhi(u1.x), bflo(u1.y), bfhi(u1.y));
                hz = make_float4(bflo(u2.x), bfhi(u2.x), bflo(u2.y), bfhi(u2.y));
            } else {
                const float4* h = (const float4*)(ent + (size_t)her.x * (3 * HID));
                hx = h[j]; hy = h[16 + j]; hz = h[32 + j];
            }
            const uint4* qr = (const uint4*)(quat16 + (size_t)her.y * HID + 4 * j);
            uint4 qa = qr[0], qb = qr[1];
            float4 q0 = make_float4(bflo(qa.x), bfhi(qa.x), bflo(qa.y), bfhi(qa.y));
            float4 q1 = make_float4(bflo(qa.z), bfhi(qa.z), bflo(qa.w), bfhi(qa.w));
            float4 q2 = make_float4(bflo(qb.x), bfhi(qb.x), bflo(qb.y), bfhi(qb.y));
            float4 q3 = make_float4(bflo(qb.z), bfhi(qb.z), bflo(qb.w), bfhi(qb.w));

            float4 qx, qy, qz, qw;
            float p = 0.0f;
            #define DO_DIM(F, Q) { \
                float ex = hx.F, ey = hy.F, ez = hz.F; \
                float w = Q.x, ux = Q.y, uy = Q.z, uz = Q.w; \
                float rqx = w * ex + uy * ez - uz * ey; \
                float rqy = w * ey + uz * ex - ux * ez; \
                float rqz = w * ez + ux * ey - uy * ex; \
                float rqw = -(ux * ex + uy * ey + uz * ez); \
                p += kx.F * rqx + ky.F * rqy + kz.F * rqz; \
                qx.F = rqx; qy.F = rqy; qz.F = rqz; qw.F = rqw; }
            DO_DIM(x, q0)
            DO_DIM(y, q1)
            DO_DIM(z, q2)
            DO_DIM(w, q3)
            #undef DO_DIM

            p += __shfl_xor(p, 1, 64);
            p += __shfl_xor(p, 2, 64);
            p += __shfl_xor(p, 4, 64);
            p += __shfl_xor(p, 8, 64);

            float pe = valid ? __expf(p * 0.0625f) : 0.0f;
            dnm += pe;
            ax.x += pe * qx.x; ax.y += pe * qx.y; ax.z += pe * qx.z; ax.w += pe * qx.w;
            ay.x += pe * qy.x; ay.y += pe * qy.y; ay.z += pe * qy.z; ay.w += pe * qy.w;
            az.x += pe * qz.x; az.y += pe * qz.y; az.z += pe * qz.z; az.w += pe * qz.w;
            aw.x += pe * qw.x; aw.y += pe * qw.y; aw.z += pe * qw.z; aw.w += pe * qw.w;
        }

        #pragma unroll
        for (int mask = 16; mask <= 32; mask <<= 1) {
            dnm += __shfl_xor(dnm, mask, 64);
            ax.x += __shfl_xor(ax.x, mask, 64); ax.y += __shfl_xor(ax.y, mask, 64);
            ax.z += __shfl_xor(ax.z, mask, 64); ax.w += __shfl_xor(ax.w, mask, 64);
            ay.x += __shfl_xor(ay.x, mask, 64); ay.y += __shfl_xor(ay.y, mask, 64);
            ay.z += __shfl_xor(ay.z, mask, 64); ay.w += __shfl_xor(ay.w, mask, 64);
            az.x += __shfl_xor(az.x, mask, 64); az.y += __shfl_xor(az.y, mask, 64);
            az.z += __shfl_xor(az.z, mask, 64); az.w += __shfl_xor(az.w, mask, 64);
            aw.x += __shfl_xor(aw.x, mask, 64); aw.y += __shfl_xor(aw.y, mask, 64);
            aw.z += __shfl_xor(aw.z, mask, 64); aw.w += __shfl_xor(aw.w, mask, 64);
        }

        float inv = (dnm > 0.0f) ? 1.0f / dnm : 0.0f;
        float4 lo = (sub & 1) ? ay : ax;
        float4 hi = (sub & 1) ? aw : az;
        float4 val = (sub & 2) ? hi : lo;
        val.x *= inv; val.y *= inv; val.z *= inv; val.w *= inv;
        o4[lane] = val;
    }
}

extern "C" void kernel_launch(void* const* d_in, const int* in_sizes, int n_in,
                              void* d_out, int out_size, void* d_ws, size_t ws_size,
                              hipStream_t stream) {
    const float* ent  = (const float*)d_in[0];
    const float* rel  = (const float*)d_in[1];
    const int*   eidx = (const int*)d_in[2];
    float* out = (float*)d_out;

    const int n_ent = in_sizes[0] / (3 * HID);
    const int n_rel = in_sizes[1] / (4 * HID);
    const int E     = in_sizes[2] / 3;

    // Workspace layout
    uint8_t* wp = (uint8_t*)d_ws;
    int2* hr     = (int2*)wp;                        wp += (size_t)E * sizeof(int2);
    int*  hist   = (int*)wp;                         wp += (size_t)n_ent * 4;
    int*  base   = (int*)wp;                         wp += (size_t)(n_ent + 1) * 4;
    int*  base2  = (int*)wp;                         wp += (size_t)n_ent * 4;
    int*  partial= (int*)wp;                         wp += 256 * 4;
    wp = (uint8_t*)(((uintptr_t)wp + 15) & ~(uintptr_t)15);
    uint2* quat16 = (uint2*)wp;                      wp += (size_t)n_rel * HID * sizeof(uint2);
    wp = (uint8_t*)(((uintptr_t)wp + 15) & ~(uintptr_t)15);
    uint4* ent16 = (uint4*)wp;                       wp += (size_t)n_ent * 3 * HID * 2;
    const bool use16 = ((size_t)(wp - (uint8_t*)d_ws) <= ws_size);

    hipMemsetAsync(hist, 0, (size_t)n_ent * sizeof(int), stream);

    const int qblocks = (n_rel * HID + 255) / 256;
    const int eblocks = (E + 255) / 256;
    const int nconv   = use16 ? (n_ent * 3 * HID / 8) : 0;   // uint4 units
    const int cblocks = (nconv + 255) / 256;
    prep<<<qblocks + eblocks + cblocks, 256, 0, stream>>>(
        rel, quat16, n_rel, eidx, E, hist, ent, ent16, nconv, qblocks, eblocks);

    const int nb = (n_ent + 255) / 256;
    scan1<<<nb, 256, 0, stream>>>(hist, base, partial, n_ent);
    scan23<<<(n_ent + 1 + 255) / 256, 256, 0, stream>>>(base, base2, partial, nb, n_ent, E);

    scatter_hr<<<eblocks, 256, 0, stream>>>(eidx, E, base2, hr);

    if (use16) {
        seg_reduce<true><<<2048, 256, 0, stream>>>(ent, (const uint2*)ent16, quat16,
                                                   hr, base, n_ent, out);
    } else {
        seg_reduce<false><<<2048, 256, 0, stream>>>(ent, nullptr, quat16,
                                                    hr, base, n_ent, out);
    }
}